// Round 7
// baseline (303.685 us; speedup 1.0000x reference)
//
#include <hip/hip_runtime.h>
#include <hip/hip_bf16.h>
#include <math.h>

#define N0v 200000
#define N1v 50000
#define N2v 10000
#define Dv  256
#define Cv  40
#define DEGv 10

typedef __attribute__((ext_vector_type(8))) short          s16x8;
typedef __attribute__((ext_vector_type(8))) unsigned short u16x8;
typedef __attribute__((ext_vector_type(4))) float          f32x4;

static __device__ __forceinline__ unsigned short f2bf(float f) {
    __hip_bfloat16 h = __float2bfloat16(f);
    return *reinterpret_cast<unsigned short*>(&h);
}
static __device__ __forceinline__ float bf2f(unsigned short u) {
    __hip_bfloat16 h = *reinterpret_cast<__hip_bfloat16*>(&u);
    return __bfloat162float(h);
}

// async global -> LDS, 16B/lane, wave-uniform LDS base + lane*16 dest
static __device__ __forceinline__ void gload16(const void* g, void* l) {
    __builtin_amdgcn_global_load_lds(
        (const __attribute__((address_space(1))) unsigned int*)g,
        (__attribute__((address_space(3))) unsigned int*)l, 16, 0, 0);
}

// ---- weight prep: 4 pairs -> WT[n][k] bf16 (k<256 = Wl col, k>=256 = Wr col)
__global__ __launch_bounds__(256) void prep_kernel(
    const float* __restrict__ Wl0, const float* __restrict__ Wr0,
    const float* __restrict__ Wl1, const float* __restrict__ Wr1,
    const float* __restrict__ Wl2, const float* __restrict__ Wr2,
    const float* __restrict__ Wl3, const float* __restrict__ Wr3,
    unsigned short* __restrict__ WT0, unsigned short* __restrict__ WT1,
    unsigned short* __restrict__ WT2, unsigned short* __restrict__ WT3)
{
    const int idx = blockIdx.x;
    const int p = idx >> 8;
    const int n = idx & 255;
    const int k = threadIdx.x;
    const float* Wl = (p == 0) ? Wl0 : (p == 1) ? Wl1 : (p == 2) ? Wl2 : Wl3;
    const float* Wr = (p == 0) ? Wr0 : (p == 1) ? Wr1 : (p == 2) ? Wr2 : Wr3;
    unsigned short* WT = (p == 0) ? WT0 : (p == 1) ? WT1 : (p == 2) ? WT2 : WT3;
    WT[(size_t)n * 512 + k]       = f2bf(Wl[(size_t)k * Dv + n]);
    WT[(size_t)n * 512 + 256 + k] = f2bf(Wr[(size_t)k * Dv + n]);
}

// ---- fused SAGE layer: gather+reduce (mean,max) into LDS A-tiles, then
// dual GEMM  out_set = [relu]( [agg_set | x_tgt] @ WT_set^T + b_set ).
// BM=64 targets/block, BN=256 (full), K=512, 8 waves = 2 sets x 2M x 2N.
// A LDS: [set][64][256] bf16, slot-XOR swizzled (slot^((row&7)) on 16B slots).
// B LDS: double-buffered BK=32, [buf][set][256][32], slot^((n>>1)&3) swizzle,
// staged via global_load_lds (linear dest, pre-swizzled source — rule 21).
template<int L0T, int RELU>
__global__ __launch_bounds__(512, 2) void fused_sage_kernel(
    const float* __restrict__ x,
    const unsigned short* __restrict__ gm, const unsigned short* __restrict__ gx,
    const int* __restrict__ rowarr,
    const unsigned short* __restrict__ WTm, const unsigned short* __restrict__ WTx,
    const float* __restrict__ bm, const float* __restrict__ bx,
    unsigned short* __restrict__ outm, unsigned short* __restrict__ outx,
    int M, int ldc)
{
    __shared__ unsigned short Asb[2][64][256];     // 64 KB
    __shared__ unsigned short Bsb[2][2][256][32];  // 64 KB

    const int tid  = threadIdx.x;
    const int lane = tid & 63;
    const int w    = tid >> 6;
    const int m0   = blockIdx.x * 64;

    // B-stage: id = g*512+tid -> set=id>>10, n=(id>>2)&255, sl=id&3.
    // LDS dest linear at elems id*8 (wave-uniform base + lane*16B).
#define STAGE_B(bufv, k0v)                                                        \
    {                                                                             \
        _Pragma("unroll")                                                         \
        for (int g = 0; g < 4; ++g) {                                             \
            const int id  = g * 512 + tid;                                        \
            const int st  = id >> 10;                                             \
            const int id2 = id & 1023;                                            \
            const int n   = id2 >> 2;                                             \
            const int sl  = id2 & 3;                                              \
            const unsigned short* srcp = (st ? WTx : WTm) + (size_t)n * 512 +     \
                                         (k0v) + ((sl ^ ((n >> 1) & 3)) << 3);    \
            unsigned short* ldst = &Bsb[bufv][0][0][0] + (size_t)(g * 512 + w * 64) * 8; \
            gload16(srcp, ldst);                                                  \
        }                                                                         \
    }

    // issue first B tile now — DMA overlaps the whole gather phase
    STAGE_B(0, 0);

    // ---- gather + reduce phase: wave w owns local rows w*8 .. w*8+7 ----
    {
        const int t0 = m0 + w * 8;
        const bool fast = (t0 + 7 <= M - 1);
        int i0 = 0, i1 = 0;
        if (fast) {
            i0 = rowarr[t0 * DEGv + lane];                 // indices flat 0..63
            i1 = rowarr[t0 * DEGv + 64 + (lane & 15)];     // flat 64..79
        }
        for (int i = 0; i < 8; ++i) {
            const int lr = w * 8 + i;
            const int t  = min(m0 + lr, M - 1);
            float s0 = 0.f, s1 = 0.f, s2 = 0.f, s3 = 0.f;
            float x0 = -INFINITY, x1 = -INFINITY, x2 = -INFINITY, x3 = -INFINITY;
#pragma unroll
            for (int k = 0; k < DEGv; ++k) {
                int r;
                if (fast) {
                    const int flat = i * DEGv + k;
                    r = (flat < 64) ? __shfl(i0, flat) : __shfl(i1, flat - 64);
                } else {
                    r = rowarr[t * DEGv + k];
                }
                if (L0T) {
                    const float4 v = ((const float4*)x)[(size_t)r * 64 + lane];
                    s0 += v.x; s1 += v.y; s2 += v.z; s3 += v.w;
                    x0 = fmaxf(x0, v.x); x1 = fmaxf(x1, v.y);
                    x2 = fmaxf(x2, v.z); x3 = fmaxf(x3, v.w);
                } else {
                    const uint2 a = *(const uint2*)(gm + (size_t)r * Dv + lane * 4);
                    const uint2 b = *(const uint2*)(gx + (size_t)r * Dv + lane * 4);
                    s0 += bf2f((unsigned short)(a.x & 0xffff));
                    s1 += bf2f((unsigned short)(a.x >> 16));
                    s2 += bf2f((unsigned short)(a.y & 0xffff));
                    s3 += bf2f((unsigned short)(a.y >> 16));
                    x0 = fmaxf(x0, bf2f((unsigned short)(b.x & 0xffff)));
                    x1 = fmaxf(x1, bf2f((unsigned short)(b.x >> 16)));
                    x2 = fmaxf(x2, bf2f((unsigned short)(b.y & 0xffff)));
                    x3 = fmaxf(x3, bf2f((unsigned short)(b.y >> 16)));
                }
            }
            const float inv = 1.0f / DEGv;
            unsigned short om4[4] = { f2bf(s0 * inv), f2bf(s1 * inv), f2bf(s2 * inv), f2bf(s3 * inv) };
            unsigned short ox4[4] = { f2bf(x0), f2bf(x1), f2bf(x2), f2bf(x3) };
            // lane c covers cols 4c..4c+3: 16B-slot c>>1, swizzled ^(lr&7), half c&1
            const int eoff = (((lane >> 1) ^ (lr & 7)) << 3) + ((lane & 1) << 2);
            *(uint2*)(&Asb[0][lr][0] + eoff) = *(const uint2*)om4;
            *(uint2*)(&Asb[1][lr][0] + eoff) = *(const uint2*)ox4;
        }
    }

    __syncthreads();   // drains gather ds_writes + buf0 DMA

    // ---- GEMM phase ----
    const int set  = w >> 2;
    const int wrow = (w >> 1) & 1;
    const int wcol = w & 1;
    const int q    = lane >> 4;
    const int fr   = lane & 15;

    f32x4 acc[2][8] = {};

    int cur = 0;
    for (int step = 0; step < 16; ++step) {
        const int k0 = step * 32;
        if (step < 15) STAGE_B(cur ^ 1, k0 + 32);

        s16x8 af[2];
        if (k0 < 256) {
            // agg half from LDS (swizzled)
#pragma unroll
            for (int i = 0; i < 2; ++i) {
                const int r = wrow * 32 + i * 16 + fr;
                const int slot = ((k0 >> 3) + q) ^ (r & 7);
                af[i] = *(const s16x8*)(&Asb[set][r][0] + (slot << 3));
            }
        } else {
            // x_tgt half straight from global f32 -> bf16 fragment
#pragma unroll
            for (int i = 0; i < 2; ++i) {
                const int t = min(m0 + wrow * 32 + i * 16 + fr, M - 1);
                const float* p = x + (size_t)t * Dv + (k0 - 256) + q * 8;
                const float4 u0 = *(const float4*)p;
                const float4 u1 = *(const float4*)(p + 4);
                unsigned short e[8] = { f2bf(u0.x), f2bf(u0.y), f2bf(u0.z), f2bf(u0.w),
                                        f2bf(u1.x), f2bf(u1.y), f2bf(u1.z), f2bf(u1.w) };
                af[i] = *(const s16x8*)e;
            }
        }

#pragma unroll
        for (int j = 0; j < 8; ++j) {
            const int n = wcol * 128 + j * 16 + fr;
            const int slotb = q ^ ((n >> 1) & 3);
            const s16x8 bv = *(const s16x8*)(&Bsb[cur][set][n][0] + (slotb << 3));
#pragma unroll
            for (int i = 0; i < 2; ++i)
                acc[i][j] = __builtin_amdgcn_mfma_f32_16x16x32_bf16(af[i], bv, acc[i][j], 0, 0, 0);
        }
        __syncthreads();
        cur ^= 1;
    }

    // epilogue: C/D map col=lane&15, row=(lane>>4)*4+reg
    const float* bias = set ? bx : bm;
    unsigned short* dst = set ? outx : outm;
#pragma unroll
    for (int i = 0; i < 2; ++i) {
#pragma unroll
        for (int reg = 0; reg < 4; ++reg) {
            const int gr = m0 + wrow * 32 + i * 16 + q * 4 + reg;
            if (gr < M) {
#pragma unroll
                for (int j = 0; j < 8; ++j) {
                    const int gc = wcol * 128 + j * 16 + fr;
                    float v = acc[i][j][reg] + bias[gc];
                    if (RELU) v = fmaxf(v, 0.0f);
                    dst[(size_t)gr * ldc + gc] = f2bf(v);
                }
            }
        }
    }
#undef STAGE_B
}

// ---- post: logits = ocat(bf16, 10000x512) @ W_post(512x40) + b_post; log_softmax.
__global__ __launch_bounds__(256) void post_kernel(
    const unsigned short* __restrict__ ocat, const float* __restrict__ Wp,
    const float* __restrict__ bp, float* __restrict__ out, int nrows)
{
    __shared__ float sW[512 * 40];        // 80 KB
    __shared__ float sP[7][32][40];       // 35 KB partials (q=1..7)
    __shared__ float sb[Cv];

    const int tid = threadIdx.x;

    for (int i = tid; i < 5120; i += 256)
        ((float4*)sW)[i] = ((const float4*)Wp)[i];
    if (tid < Cv) sb[tid] = bp[tid];
    __syncthreads();

    const int q = tid >> 5;               // k-split 0..7 (64 k each)
    const int r = tid & 31;               // local row
    const int t = blockIdx.x * 32 + r;
    const bool valid = (t < nrows);

    float acc[Cv] = {};
    if (valid) {
        const unsigned short* prow = ocat + (size_t)t * 512 + q * 64;
        for (int kk = 0; kk < 64; kk += 8) {
            u16x8 v = *(const u16x8*)(prow + kk);
            const float* wbase = &sW[(q * 64 + kk) * Cv];
#pragma unroll
            for (int e = 0; e < 8; ++e) {
                const float xv = bf2f(v[e]);
                const float* wr_ = wbase + e * Cv;
#pragma unroll
                for (int c4 = 0; c4 < Cv; c4 += 4) {
                    f32x4 wv = *(const f32x4*)(wr_ + c4);
                    acc[c4 + 0] += xv * wv[0];
                    acc[c4 + 1] += xv * wv[1];
                    acc[c4 + 2] += xv * wv[2];
                    acc[c4 + 3] += xv * wv[3];
                }
            }
        }
    }

    if (q > 0) {
#pragma unroll
        for (int c4 = 0; c4 < Cv; c4 += 4)
            *(f32x4*)&sP[q - 1][r][c4] = *(f32x4*)&acc[c4];
    }
    __syncthreads();

    if (q == 0 && valid) {
#pragma unroll
        for (int p = 0; p < 7; ++p)
#pragma unroll
            for (int c4 = 0; c4 < Cv; c4 += 4) {
                f32x4 pv = *(const f32x4*)&sP[p][r][c4];
                acc[c4 + 0] += pv[0];
                acc[c4 + 1] += pv[1];
                acc[c4 + 2] += pv[2];
                acc[c4 + 3] += pv[3];
            }
        float m = -INFINITY;
#pragma unroll
        for (int c = 0; c < Cv; ++c) { acc[c] += sb[c]; m = fmaxf(m, acc[c]); }
        float s = 0.0f;
#pragma unroll
        for (int c = 0; c < Cv; ++c) s += expf(acc[c] - m);
        const float lse = m + logf(s);
        float* dst = out + (size_t)t * Cv;
#pragma unroll
        for (int c4 = 0; c4 < Cv; c4 += 4) {
            float o[4] = { acc[c4] - lse, acc[c4 + 1] - lse, acc[c4 + 2] - lse, acc[c4 + 3] - lse };
            *(float4*)(dst + c4) = *(float4*)o;
        }
    }
}

extern "C" void kernel_launch(void* const* d_in, const int* in_sizes, int n_in,
                              void* d_out, int out_size, void* d_ws, size_t ws_size,
                              hipStream_t stream)
{
    const float* x      = (const float*)d_in[0];
    const int*   ei0    = (const int*)d_in[1];
    const int*   ei1    = (const int*)d_in[2];
    const float* Wl_m0  = (const float*)d_in[3];
    const float* Wr_m0  = (const float*)d_in[4];
    const float* b_m0   = (const float*)d_in[5];
    const float* Wl_x0  = (const float*)d_in[6];
    const float* Wr_x0  = (const float*)d_in[7];
    const float* b_x0   = (const float*)d_in[8];
    const float* Wl_m1  = (const float*)d_in[9];
    const float* Wr_m1  = (const float*)d_in[10];
    const float* b_m1   = (const float*)d_in[11];
    const float* Wl_x1  = (const float*)d_in[12];
    const float* Wr_x1  = (const float*)d_in[13];
    const float* b_x1   = (const float*)d_in[14];
    const float* W_post = (const float*)d_in[15];
    const float* b_post = (const float*)d_in[16];
    float* out = (float*)d_out;

    const int* row0 = ei0;   // edge_index0[0]
    const int* row1 = ei1;   // edge_index1[0]

    // workspace layout
    char* ws = (char*)d_ws;
    unsigned short* hm   = (unsigned short*)(ws);                          // 25.6 MB
    unsigned short* hx   = hm + (size_t)N1v * Dv;                          // 25.6 MB
    unsigned short* ocat = hx + (size_t)N1v * Dv;                          // 10.24 MB
    unsigned short* WT0m = ocat + (size_t)N2v * 2 * Dv;
    unsigned short* WT0x = WT0m + (size_t)256 * 512;
    unsigned short* WT1m = WT0x + (size_t)256 * 512;
    unsigned short* WT1x = WT1m + (size_t)256 * 512;

    // 1) weight transpose+convert
    prep_kernel<<<1024, dim3(256), 0, stream>>>(
        Wl_m0, Wr_m0, Wl_x0, Wr_x0, Wl_m1, Wr_m1, Wl_x1, Wr_x1,
        WT0m, WT0x, WT1m, WT1x);

    // 2) layer 0: gather x (f32) + mean/max + dual GEMM -> hm, hx (bf16)
    fused_sage_kernel<1, 1><<<(N1v + 63) / 64, dim3(512), 0, stream>>>(
        x, hm, hm, row0, WT0m, WT0x, b_m0, b_x0, hm, hx, N1v, Dv);

    // 3) layer 1: gather hm/hx (bf16) + mean/max + dual GEMM -> ocat (bf16)
    fused_sage_kernel<0, 0><<<(N2v + 63) / 64, dim3(512), 0, stream>>>(
        x, hm, hx, row1, WT1m, WT1x, b_m1, b_x1, ocat, ocat + Dv, N2v, 2 * Dv);

    // 4) post GEMV + log_softmax
    post_kernel<<<(N2v + 31) / 32, dim3(256), 0, stream>>>(ocat, W_post, b_post, out, N2v);
}

// Round 8
// 226.576 us; speedup vs baseline: 1.3403x; 1.3403x over previous
//
#include <hip/hip_runtime.h>
#include <hip/hip_bf16.h>
#include <math.h>

#define N0v 200000
#define N1v 50000
#define N2v 10000
#define Dv  256
#define Cv  40
#define DEGv 10

typedef __attribute__((ext_vector_type(8))) short          s16x8;
typedef __attribute__((ext_vector_type(8))) unsigned short u16x8;
typedef __attribute__((ext_vector_type(4))) float          f32x4;

static __device__ __forceinline__ unsigned short f2bf(float f) {
    __hip_bfloat16 h = __float2bfloat16(f);
    return *reinterpret_cast<unsigned short*>(&h);
}
static __device__ __forceinline__ float bf2f(unsigned short u) {
    __hip_bfloat16 h = *reinterpret_cast<__hip_bfloat16*>(&u);
    return __bfloat162float(h);
}

// async global -> LDS, 16B/lane, wave-uniform LDS base + lane*16 dest
static __device__ __forceinline__ void gload16(const void* g, void* l) {
    __builtin_amdgcn_global_load_lds(
        (const __attribute__((address_space(1))) unsigned int*)g,
        (__attribute__((address_space(3))) unsigned int*)l, 16, 0, 0);
}

// ---- fused: agg0 (blocks [0,12500)) + weight prep (blocks [12500,13524))
__global__ __launch_bounds__(256) void agg0_prep_kernel(
    const float* __restrict__ x, const int* __restrict__ row,
    unsigned short* __restrict__ om, unsigned short* __restrict__ ox,
    unsigned short* __restrict__ xtb,
    const float* __restrict__ Wl0, const float* __restrict__ Wr0,
    const float* __restrict__ Wl1, const float* __restrict__ Wr1,
    const float* __restrict__ Wl2, const float* __restrict__ Wr2,
    const float* __restrict__ Wl3, const float* __restrict__ Wr3,
    unsigned short* __restrict__ WT0, unsigned short* __restrict__ WT1,
    unsigned short* __restrict__ WT2, unsigned short* __restrict__ WT3)
{
    const int b = blockIdx.x;
    if (b < 12500) {
        const int t = b * 4 + (threadIdx.x >> 6);
        const int c = threadIdx.x & 63;
        const int eb = t * DEGv;
        float4 s = make_float4(0.f, 0.f, 0.f, 0.f);
        float4 mx = make_float4(-INFINITY, -INFINITY, -INFINITY, -INFINITY);
#pragma unroll
        for (int k = 0; k < DEGv; ++k) {
            const int r = row[eb + k];
            float4 v = ((const float4*)x)[(size_t)r * 64 + c];
            s.x += v.x; s.y += v.y; s.z += v.z; s.w += v.w;
            mx.x = fmaxf(mx.x, v.x); mx.y = fmaxf(mx.y, v.y);
            mx.z = fmaxf(mx.z, v.z); mx.w = fmaxf(mx.w, v.w);
        }
        const float inv = 1.0f / DEGv;
        unsigned short osum[4] = { f2bf(s.x * inv), f2bf(s.y * inv), f2bf(s.z * inv), f2bf(s.w * inv) };
        unsigned short omax[4] = { f2bf(mx.x), f2bf(mx.y), f2bf(mx.z), f2bf(mx.w) };
        *(uint2*)&om[(size_t)t * Dv + c * 4] = *(uint2*)osum;
        *(uint2*)&ox[(size_t)t * Dv + c * 4] = *(uint2*)omax;

        float4 v = ((const float4*)x)[(size_t)t * 64 + c];
        unsigned short o[4] = { f2bf(v.x), f2bf(v.y), f2bf(v.z), f2bf(v.w) };
        *(uint2*)&xtb[(size_t)t * Dv + c * 4] = *(uint2*)o;
    } else {
        const int idx = b - 12500;
        const int p = idx >> 8;
        const int n = idx & 255;
        const int k = threadIdx.x;
        const float* Wl = (p == 0) ? Wl0 : (p == 1) ? Wl1 : (p == 2) ? Wl2 : Wl3;
        const float* Wr = (p == 0) ? Wr0 : (p == 1) ? Wr1 : (p == 2) ? Wr2 : Wr3;
        unsigned short* WT = (p == 0) ? WT0 : (p == 1) ? WT1 : (p == 2) ? WT2 : WT3;
        WT[(size_t)n * 512 + k]       = f2bf(Wl[(size_t)k * Dv + n]);
        WT[(size_t)n * 512 + 256 + k] = f2bf(Wr[(size_t)k * Dv + n]);
    }
}

// ---- layer-1 aggregation: gather bf16 (u16x8/lane), write mean & max bf16
__global__ __launch_bounds__(256) void agg1_kernel(
    const unsigned short* __restrict__ hm, const unsigned short* __restrict__ hx,
    const int* __restrict__ row,
    unsigned short* __restrict__ om, unsigned short* __restrict__ ox)
{
    const int t = blockIdx.x * 8 + (threadIdx.x >> 5);
    const int c = threadIdx.x & 31;
    const int eb = t * DEGv;
    float s[8] = {};
    float mx[8] = { -INFINITY, -INFINITY, -INFINITY, -INFINITY,
                    -INFINITY, -INFINITY, -INFINITY, -INFINITY };
#pragma unroll
    for (int k = 0; k < DEGv; ++k) {
        const int r = row[eb + k];
        u16x8 vm = ((const u16x8*)hm)[(size_t)r * 32 + c];
        u16x8 vx = ((const u16x8*)hx)[(size_t)r * 32 + c];
#pragma unroll
        for (int j = 0; j < 8; ++j) {
            s[j]  += bf2f(vm[j]);
            mx[j]  = fmaxf(mx[j], bf2f(vx[j]));
        }
    }
    const float inv = 1.0f / DEGv;
    unsigned short osum[8], omax[8];
#pragma unroll
    for (int j = 0; j < 8; ++j) { osum[j] = f2bf(s[j] * inv); omax[j] = f2bf(mx[j]); }
    *(u16x8*)&om[(size_t)t * Dv + c * 8] = *(u16x8*)osum;
    *(u16x8*)&ox[(size_t)t * Dv + c * 8] = *(u16x8*)omax;
}

// ---- bf16 MFMA GEMM: out_z = [relu]( [A1_z|A2] (Mx512) @ WT_z^T + bias_z )
// BM=128, BN=256, BK=32 DOUBLE-BUFFERED (T3-minimal 2-phase: stage next tile
// before computing current; one __syncthreads (vmcnt0+barrier) per step).
// LDS paired-line layout: line L (64 elems) holds rows {2L, 2L+1} x 32 k;
// phys 8-elem slot s of line L holds logical slot (s ^ (L&7)) where logical
// slot sigma = (row&1)*4 + kslot. Conflict-free b128 frag reads; staging is
// linear-dest gload16 with pre-swizzled per-thread source (rule 21).
template<int RELU, int OUTBF>
__global__ __launch_bounds__(256) void gemm_mfma_kernel(
    const unsigned short* __restrict__ A1a, const unsigned short* __restrict__ A1b,
    const unsigned short* __restrict__ A2,
    const unsigned short* __restrict__ WTa, const unsigned short* __restrict__ WTb,
    const float* __restrict__ biasa, const float* __restrict__ biasb,
    void* outa, void* outb, int M, int ldc, int col_step)
{
    __shared__ unsigned short Asb[2][4096];   // 2 x 8 KB  (128 rows x 32 k)
    __shared__ unsigned short Bsb[2][8192];   // 2 x 16 KB (256 rows x 32 k)

    const int z = blockIdx.z;
    const unsigned short* A1 = z ? A1b : A1a;
    const unsigned short* WT = z ? WTb : WTa;
    const float* bias = z ? biasb : biasa;
    void* outp = z ? outb : outa;
    const int col_off = z * col_step;

    const int tid  = threadIdx.x;
    const int lane = tid & 63;
    const int wrow = (tid >> 7) & 1;          // wave M position (x64)
    const int wcol = (tid >> 6) & 1;          // wave N position (x128)
    const int m0   = blockIdx.x * 128;

    // ---- staging descriptors (per-thread constants) ----
    // A: positions p = tid, tid+256  (512 x 16B = 8 KB)
    const unsigned short* pA1s[2];
    const unsigned short* pA2s[2];
    int ldsA[2];
#pragma unroll
    for (int c = 0; c < 2; ++c) {
        const int p = tid + c * 256;
        const int L = p >> 3, s = p & 7;
        const int sig = s ^ (L & 7);
        int gm = m0 + 2 * L + (sig >> 2);
        if (gm >= M) gm = M - 1;
        const int gk = (sig & 3) << 3;
        pA1s[c] = A1 + (size_t)gm * Dv + gk;
        pA2s[c] = A2 + (size_t)gm * Dv + gk;
        ldsA[c] = p * 8;
    }
    // B: positions p = tid + {0,256,512,768}  (1024 x 16B = 16 KB)
    const unsigned short* pBs[4];
    int ldsB[4];
#pragma unroll
    for (int c = 0; c < 4; ++c) {
        const int p = tid + c * 256;
        const int L = p >> 3, s = p & 7;
        const int sig = s ^ (L & 7);
        const int n = 2 * L + (sig >> 2);
        const int gk = (sig & 3) << 3;
        pBs[c] = WT + (size_t)n * 512 + gk;
        ldsB[c] = p * 8;
    }

#define STAGE(bufv, k0v)                                                     \
    {                                                                        \
        if ((k0v) < 256) {                                                   \
            gload16(pA1s[0] + (k0v), &Asb[bufv][ldsA[0]]);                   \
            gload16(pA1s[1] + (k0v), &Asb[bufv][ldsA[1]]);                   \
        } else {                                                             \
            gload16(pA2s[0] + ((k0v) - 256), &Asb[bufv][ldsA[0]]);           \
            gload16(pA2s[1] + ((k0v) - 256), &Asb[bufv][ldsA[1]]);           \
        }                                                                    \
        _Pragma("unroll")                                                    \
        for (int c = 0; c < 4; ++c)                                          \
            gload16(pBs[c] + (k0v), &Bsb[bufv][ldsB[c]]);                    \
    }

    // ---- fragment read offsets (per-lane constants) ----
    const int q  = lane >> 4;
    const int fr = lane & 15;
    int aoff[4];
#pragma unroll
    for (int i = 0; i < 4; ++i) {
        const int r = wrow * 64 + i * 16 + fr;
        const int L = r >> 1;
        const int s = (((r & 1) << 2) + q) ^ (L & 7);
        aoff[i] = L * 64 + s * 8;
    }
    int boff[8];
#pragma unroll
    for (int j = 0; j < 8; ++j) {
        const int n = wcol * 128 + j * 16 + fr;
        const int L = n >> 1;
        const int s = (((n & 1) << 2) + q) ^ (L & 7);
        boff[j] = L * 64 + s * 8;
    }

    f32x4 acc[4][8] = {};

    // ---- pipelined K loop: 16 steps of BK=32 ----
    STAGE(0, 0);
    __syncthreads();
    int cur = 0;
    for (int step = 0; step < 16; ++step) {
        if (step < 15) STAGE(cur ^ 1, (step + 1) * 32);

        s16x8 af[4];
#pragma unroll
        for (int i = 0; i < 4; ++i)
            af[i] = *(const s16x8*)&Asb[cur][aoff[i]];
#pragma unroll
        for (int j = 0; j < 8; ++j) {
            const s16x8 bv = *(const s16x8*)&Bsb[cur][boff[j]];
#pragma unroll
            for (int i = 0; i < 4; ++i)
                acc[i][j] = __builtin_amdgcn_mfma_f32_16x16x32_bf16(af[i], bv, acc[i][j], 0, 0, 0);
        }
        __syncthreads();   // drains vmcnt(0) (next tile DMA) + lgkmcnt
        cur ^= 1;
    }
#undef STAGE

    // epilogue: C/D map col=lane&15, row=(lane>>4)*4+reg
#pragma unroll
    for (int i = 0; i < 4; ++i) {
#pragma unroll
        for (int reg = 0; reg < 4; ++reg) {
            const int gr = m0 + wrow * 64 + i * 16 + q * 4 + reg;
            if (gr < M) {
#pragma unroll
                for (int j = 0; j < 8; ++j) {
                    const int gc = wcol * 128 + j * 16 + fr;
                    float v = acc[i][j][reg] + bias[gc];
                    if (RELU) v = fmaxf(v, 0.0f);
                    if (OUTBF)
                        ((unsigned short*)outp)[(size_t)gr * ldc + col_off + gc] = f2bf(v);
                    else
                        ((float*)outp)[(size_t)gr * ldc + col_off + gc] = v;
                }
            }
        }
    }
}

// ---- post: logits = ocat(bf16, 10000x512) @ W_post(512x40) + b_post; log_softmax.
__global__ __launch_bounds__(256) void post_kernel(
    const unsigned short* __restrict__ ocat, const float* __restrict__ Wp,
    const float* __restrict__ bp, float* __restrict__ out, int nrows)
{
    __shared__ float sW[512 * 40];        // 80 KB
    __shared__ float sP[7][32][40];       // 35 KB partials (q=1..7)
    __shared__ float sb[Cv];

    const int tid = threadIdx.x;

    for (int i = tid; i < 5120; i += 256)
        ((float4*)sW)[i] = ((const float4*)Wp)[i];
    if (tid < Cv) sb[tid] = bp[tid];
    __syncthreads();

    const int q = tid >> 5;               // k-split 0..7 (64 k each)
    const int r = tid & 31;               // local row
    const int t = blockIdx.x * 32 + r;
    const bool valid = (t < nrows);

    float acc[Cv] = {};
    if (valid) {
        const unsigned short* prow = ocat + (size_t)t * 512 + q * 64;
        for (int kk = 0; kk < 64; kk += 8) {
            u16x8 v = *(const u16x8*)(prow + kk);
            const float* wbase = &sW[(q * 64 + kk) * Cv];
#pragma unroll
            for (int e = 0; e < 8; ++e) {
                const float xv = bf2f(v[e]);
                const float* wr_ = wbase + e * Cv;
#pragma unroll
                for (int c4 = 0; c4 < Cv; c4 += 4) {
                    f32x4 wv = *(const f32x4*)(wr_ + c4);
                    acc[c4 + 0] += xv * wv[0];
                    acc[c4 + 1] += xv * wv[1];
                    acc[c4 + 2] += xv * wv[2];
                    acc[c4 + 3] += xv * wv[3];
                }
            }
        }
    }

    if (q > 0) {
#pragma unroll
        for (int c4 = 0; c4 < Cv; c4 += 4)
            *(f32x4*)&sP[q - 1][r][c4] = *(f32x4*)&acc[c4];
    }
    __syncthreads();

    if (q == 0 && valid) {
#pragma unroll
        for (int p = 0; p < 7; ++p)
#pragma unroll
            for (int c4 = 0; c4 < Cv; c4 += 4) {
                f32x4 pv = *(const f32x4*)&sP[p][r][c4];
                acc[c4 + 0] += pv[0];
                acc[c4 + 1] += pv[1];
                acc[c4 + 2] += pv[2];
                acc[c4 + 3] += pv[3];
            }
        float m = -INFINITY;
#pragma unroll
        for (int c = 0; c < Cv; ++c) { acc[c] += sb[c]; m = fmaxf(m, acc[c]); }
        float s = 0.0f;
#pragma unroll
        for (int c = 0; c < Cv; ++c) s += expf(acc[c] - m);
        const float lse = m + logf(s);
        float* dst = out + (size_t)t * Cv;
#pragma unroll
        for (int c4 = 0; c4 < Cv; c4 += 4) {
            float o[4] = { acc[c4] - lse, acc[c4 + 1] - lse, acc[c4 + 2] - lse, acc[c4 + 3] - lse };
            *(float4*)(dst + c4) = *(float4*)o;
        }
    }
}

extern "C" void kernel_launch(void* const* d_in, const int* in_sizes, int n_in,
                              void* d_out, int out_size, void* d_ws, size_t ws_size,
                              hipStream_t stream)
{
    const float* x      = (const float*)d_in[0];
    const int*   ei0    = (const int*)d_in[1];
    const int*   ei1    = (const int*)d_in[2];
    const float* Wl_m0  = (const float*)d_in[3];
    const float* Wr_m0  = (const float*)d_in[4];
    const float* b_m0   = (const float*)d_in[5];
    const float* Wl_x0  = (const float*)d_in[6];
    const float* Wr_x0  = (const float*)d_in[7];
    const float* b_x0   = (const float*)d_in[8];
    const float* Wl_m1  = (const float*)d_in[9];
    const float* Wr_m1  = (const float*)d_in[10];
    const float* b_m1   = (const float*)d_in[11];
    const float* Wl_x1  = (const float*)d_in[12];
    const float* Wr_x1  = (const float*)d_in[13];
    const float* b_x1   = (const float*)d_in[14];
    const float* W_post = (const float*)d_in[15];
    const float* b_post = (const float*)d_in[16];
    float* out = (float*)d_out;

    const int* row0 = ei0;   // edge_index0[0]
    const int* row1 = ei1;   // edge_index1[0]

    // workspace layout
    char* ws = (char*)d_ws;
    const size_t NB = (size_t)N1v * Dv * 2;                        // 25.6 MB
    unsigned short* xtb = (unsigned short*)(ws);
    unsigned short* am  = (unsigned short*)(ws + NB);
    unsigned short* ax  = (unsigned short*)(ws + 2 * NB);
    unsigned short* hm  = (unsigned short*)(ws + 3 * NB);
    unsigned short* hx  = (unsigned short*)(ws + 4 * NB);
    unsigned short* a1m = (unsigned short*)(ws + 5 * NB);
    unsigned short* a1x = a1m + (size_t)N2v * Dv;
    unsigned short* ocat = (unsigned short*)(ws + 5 * NB + (size_t)2 * N2v * Dv * 2);
    unsigned short* WT0m = ocat + (size_t)N2v * 2 * Dv;
    unsigned short* WT0x = WT0m + (size_t)256 * 512;
    unsigned short* WT1m = WT0x + (size_t)256 * 512;
    unsigned short* WT1x = WT1m + (size_t)256 * 512;

    const dim3 blk(256);

    // fused agg0 + x->bf16 + weight prep
    agg0_prep_kernel<<<12500 + 1024, blk, 0, stream>>>(
        x, row0, am, ax, xtb,
        Wl_m0, Wr_m0, Wl_x0, Wr_x0, Wl_m1, Wr_m1, Wl_x1, Wr_x1,
        WT0m, WT0x, WT1m, WT1x);

    // layer 0 (both GEMMs in one dispatch, full-N tile)
    gemm_mfma_kernel<1, 1><<<dim3((N1v + 127) / 128, 1, 2), blk, 0, stream>>>(
        am, ax, xtb, WT0m, WT0x, b_m0, b_x0, hm, hx, N1v, Dv, 0);

    // layer 1
    agg1_kernel<<<N2v / 8, blk, 0, stream>>>(hm, hx, row1, a1m, a1x);
    gemm_mfma_kernel<0, 1><<<dim3((N2v + 127) / 128, 1, 2), blk, 0, stream>>>(
        a1m, a1x, xtb, WT1m, WT1x, b_m1, b_x1, ocat, ocat, N2v, 2 * Dv, Dv);

    // post
    post_kernel<<<(N2v + 31) / 32, blk, 0, stream>>>(ocat, W_post, b_post, out, N2v);
}

// Round 9
// 217.029 us; speedup vs baseline: 1.3993x; 1.0440x over previous
//
#include <hip/hip_runtime.h>
#include <hip/hip_bf16.h>
#include <math.h>

#define N0v 200000
#define N1v 50000
#define N2v 10000
#define Dv  256
#define Cv  40
#define DEGv 10

typedef __attribute__((ext_vector_type(8))) short          s16x8;
typedef __attribute__((ext_vector_type(8))) unsigned short u16x8;
typedef __attribute__((ext_vector_type(4))) float          f32x4;

static __device__ __forceinline__ unsigned short f2bf(float f) {
    __hip_bfloat16 h = __float2bfloat16(f);
    return *reinterpret_cast<unsigned short*>(&h);
}
static __device__ __forceinline__ float bf2f(unsigned short u) {
    __hip_bfloat16 h = *reinterpret_cast<__hip_bfloat16*>(&u);
    return __bfloat162float(h);
}

// async global -> LDS, 16B/lane, wave-uniform LDS base + lane*16 dest
static __device__ __forceinline__ void gload16(const void* g, void* l) {
    __builtin_amdgcn_global_load_lds(
        (const __attribute__((address_space(1))) unsigned int*)g,
        (__attribute__((address_space(3))) unsigned int*)l, 16, 0, 0);
}

// ---- conv+prep: blocks [0,25000) convert x (200000x256 f32) -> xb bf16;
//      blocks [25000,26024) transpose 4 weight pairs -> WT[n][k] bf16.
__global__ __launch_bounds__(256) void conv_prep_kernel(
    const float* __restrict__ x, unsigned short* __restrict__ xb,
    const float* __restrict__ Wl0, const float* __restrict__ Wr0,
    const float* __restrict__ Wl1, const float* __restrict__ Wr1,
    const float* __restrict__ Wl2, const float* __restrict__ Wr2,
    const float* __restrict__ Wl3, const float* __restrict__ Wr3,
    unsigned short* __restrict__ WT0, unsigned short* __restrict__ WT1,
    unsigned short* __restrict__ WT2, unsigned short* __restrict__ WT3)
{
    const int b = blockIdx.x;
    const int tid = threadIdx.x;
    if (b < 25000) {
        const size_t i = ((size_t)b * 256 + tid) * 8;
        float4 v0 = *(const float4*)(x + i);
        float4 v1 = *(const float4*)(x + i + 4);
        unsigned short o[8] = { f2bf(v0.x), f2bf(v0.y), f2bf(v0.z), f2bf(v0.w),
                                f2bf(v1.x), f2bf(v1.y), f2bf(v1.z), f2bf(v1.w) };
        *(u16x8*)(xb + i) = *(u16x8*)o;
    } else {
        const int idx = b - 25000;
        const int p = idx >> 8;
        const int n = idx & 255;
        const float* Wl = (p == 0) ? Wl0 : (p == 1) ? Wl1 : (p == 2) ? Wl2 : Wl3;
        const float* Wr = (p == 0) ? Wr0 : (p == 1) ? Wr1 : (p == 2) ? Wr2 : Wr3;
        unsigned short* WT = (p == 0) ? WT0 : (p == 1) ? WT1 : (p == 2) ? WT2 : WT3;
        WT[(size_t)n * 512 + tid]       = f2bf(Wl[(size_t)tid * Dv + n]);
        WT[(size_t)n * 512 + 256 + tid] = f2bf(Wr[(size_t)tid * Dv + n]);
    }
}

// ---- layer-0 aggregation from bf16 table: one load feeds mean AND max.
// 8 targets/block, 32 lanes/target, u16x8 (16B) per lane.
__global__ __launch_bounds__(256) void agg0_kernel(
    const unsigned short* __restrict__ xb, const int* __restrict__ row,
    unsigned short* __restrict__ om, unsigned short* __restrict__ ox)
{
    const int t = blockIdx.x * 8 + (threadIdx.x >> 5);
    const int c = threadIdx.x & 31;
    const int eb = t * DEGv;
    float s[8] = {};
    float mx[8] = { -INFINITY, -INFINITY, -INFINITY, -INFINITY,
                    -INFINITY, -INFINITY, -INFINITY, -INFINITY };
#pragma unroll
    for (int k = 0; k < DEGv; ++k) {
        const int r = row[eb + k];
        u16x8 v = ((const u16x8*)xb)[(size_t)r * 32 + c];
#pragma unroll
        for (int j = 0; j < 8; ++j) {
            const float f = bf2f(v[j]);
            s[j] += f;
            mx[j] = fmaxf(mx[j], f);
        }
    }
    const float inv = 1.0f / DEGv;
    unsigned short osum[8], omax[8];
#pragma unroll
    for (int j = 0; j < 8; ++j) { osum[j] = f2bf(s[j] * inv); omax[j] = f2bf(mx[j]); }
    *(u16x8*)&om[(size_t)t * Dv + c * 8] = *(u16x8*)osum;
    *(u16x8*)&ox[(size_t)t * Dv + c * 8] = *(u16x8*)omax;
}

// ---- layer-1 aggregation: gather bf16 (u16x8/lane), write mean & max bf16
__global__ __launch_bounds__(256) void agg1_kernel(
    const unsigned short* __restrict__ hm, const unsigned short* __restrict__ hx,
    const int* __restrict__ row,
    unsigned short* __restrict__ om, unsigned short* __restrict__ ox)
{
    const int t = blockIdx.x * 8 + (threadIdx.x >> 5);
    const int c = threadIdx.x & 31;
    const int eb = t * DEGv;
    float s[8] = {};
    float mx[8] = { -INFINITY, -INFINITY, -INFINITY, -INFINITY,
                    -INFINITY, -INFINITY, -INFINITY, -INFINITY };
#pragma unroll
    for (int k = 0; k < DEGv; ++k) {
        const int r = row[eb + k];
        u16x8 vm = ((const u16x8*)hm)[(size_t)r * 32 + c];
        u16x8 vx = ((const u16x8*)hx)[(size_t)r * 32 + c];
#pragma unroll
        for (int j = 0; j < 8; ++j) {
            s[j]  += bf2f(vm[j]);
            mx[j]  = fmaxf(mx[j], bf2f(vx[j]));
        }
    }
    const float inv = 1.0f / DEGv;
    unsigned short osum[8], omax[8];
#pragma unroll
    for (int j = 0; j < 8; ++j) { osum[j] = f2bf(s[j] * inv); omax[j] = f2bf(mx[j]); }
    *(u16x8*)&om[(size_t)t * Dv + c * 8] = *(u16x8*)osum;
    *(u16x8*)&ox[(size_t)t * Dv + c * 8] = *(u16x8*)omax;
}

// ---- bf16 MFMA GEMM (r6-proven): out_z = [relu]([A1_z|A2] @ WT_z^T + bias_z)
// BM=128, BN=256, BK=64, 4 waves (2M x 2N), wave-tile 64x128.
// global_load_lds staging; source-side XOR swizzle (rule 21).
template<int RELU, int OUTBF>
__global__ __launch_bounds__(256) void gemm_mfma_kernel(
    const unsigned short* __restrict__ A1a, const unsigned short* __restrict__ A1b,
    const unsigned short* __restrict__ A2,
    const unsigned short* __restrict__ WTa, const unsigned short* __restrict__ WTb,
    const float* __restrict__ biasa, const float* __restrict__ biasb,
    void* outa, void* outb, int M, int ldc, int col_step)
{
    __shared__ unsigned short Asb[128 * 64];   // 16 KB
    __shared__ unsigned short Bsb[256 * 64];   // 32 KB

    const int z = blockIdx.z;
    const unsigned short* A1 = z ? A1b : A1a;
    const unsigned short* WT = z ? WTb : WTa;
    const float* bias = z ? biasb : biasa;
    void* outp = z ? outb : outa;
    const int col_off = z * col_step;

    const int tid  = threadIdx.x;
    const int lane = tid & 63;
    const int w    = tid >> 6;
    const int wrow = w >> 1;        // M position (x64)
    const int wcol = w & 1;         // N position (x128)
    const int m0   = blockIdx.x * 128;

    const int lrow = lane >> 3;
    const int scol = ((lane & 7) ^ lrow) * 8;   // swizzled source k-slot (elems)

    // A staging: wave w covers tile rows w*32 .. +31 (4 gload16)
    const unsigned short* pA1[4];
    const unsigned short* pA2[4];
    unsigned short* lA[4];
#pragma unroll
    for (int c = 0; c < 4; ++c) {
        const int r = w * 32 + c * 8 + lrow;
        int gm = m0 + r; if (gm >= M) gm = M - 1;
        pA1[c] = A1 + (size_t)gm * Dv + scol;
        pA2[c] = A2 + (size_t)gm * Dv + scol;
        lA[c] = &Asb[(w * 32 + c * 8) * 64];
    }
    // B staging: wave w covers B rows w*64 .. +63 (8 gload16)
    const unsigned short* pB[8];
    unsigned short* lB[8];
#pragma unroll
    for (int c = 0; c < 8; ++c) {
        const int r = w * 64 + c * 8 + lrow;
        pB[c] = WT + (size_t)r * 512 + scol;
        lB[c] = &Bsb[(w * 64 + c * 8) * 64];
    }

    const int fr = lane & 15;
    const int f7 = lane & 7;

    f32x4 acc[4][8] = {};

    for (int k0 = 0; k0 < 512; k0 += 64) {
        __syncthreads();             // prior ds_reads done before overwrite
        if (k0 < 256) {
#pragma unroll
            for (int c = 0; c < 4; ++c) gload16(pA1[c] + k0, lA[c]);
        } else {
#pragma unroll
            for (int c = 0; c < 4; ++c) gload16(pA2[c] + (k0 - 256), lA[c]);
        }
#pragma unroll
        for (int c = 0; c < 8; ++c) gload16(pB[c] + k0, lB[c]);
        __syncthreads();             // drains vmcnt before use

#pragma unroll
        for (int kk = 0; kk < 2; ++kk) {
            const int sl = kk * 4 + (lane >> 4);
            const int so = ((sl ^ f7) << 3);
            s16x8 af[4];
#pragma unroll
            for (int i = 0; i < 4; ++i)
                af[i] = *(const s16x8*)&Asb[(wrow * 64 + i * 16 + fr) * 64 + so];
#pragma unroll
            for (int j = 0; j < 8; ++j) {
                s16x8 bv = *(const s16x8*)&Bsb[(wcol * 128 + j * 16 + fr) * 64 + so];
#pragma unroll
                for (int i = 0; i < 4; ++i)
                    acc[i][j] = __builtin_amdgcn_mfma_f32_16x16x32_bf16(af[i], bv, acc[i][j], 0, 0, 0);
            }
        }
    }

    // epilogue: C/D map col=lane&15, row=(lane>>4)*4+reg
#pragma unroll
    for (int i = 0; i < 4; ++i) {
#pragma unroll
        for (int reg = 0; reg < 4; ++reg) {
            const int gr = m0 + wrow * 64 + i * 16 + (lane >> 4) * 4 + reg;
            if (gr < M) {
#pragma unroll
                for (int j = 0; j < 8; ++j) {
                    const int gc = wcol * 128 + j * 16 + fr;
                    float v = acc[i][j][reg] + bias[gc];
                    if (RELU) v = fmaxf(v, 0.0f);
                    if (OUTBF)
                        ((unsigned short*)outp)[(size_t)gr * ldc + col_off + gc] = f2bf(v);
                    else
                        ((float*)outp)[(size_t)gr * ldc + col_off + gc] = v;
                }
            }
        }
    }
}

// ---- post: logits = ocat(bf16, 10000x512) @ W_post(512x40) + b_post; log_softmax.
__global__ __launch_bounds__(256) void post_kernel(
    const unsigned short* __restrict__ ocat, const float* __restrict__ Wp,
    const float* __restrict__ bp, float* __restrict__ out, int nrows)
{
    __shared__ float sW[512 * 40];        // 80 KB
    __shared__ float sP[7][32][40];       // 35 KB partials (q=1..7)
    __shared__ float sb[Cv];

    const int tid = threadIdx.x;

    for (int i = tid; i < 5120; i += 256)
        ((float4*)sW)[i] = ((const float4*)Wp)[i];
    if (tid < Cv) sb[tid] = bp[tid];
    __syncthreads();

    const int q = tid >> 5;               // k-split 0..7 (64 k each)
    const int r = tid & 31;               // local row
    const int t = blockIdx.x * 32 + r;
    const bool valid = (t < nrows);

    float acc[Cv] = {};
    if (valid) {
        const unsigned short* prow = ocat + (size_t)t * 512 + q * 64;
        for (int kk = 0; kk < 64; kk += 8) {
            u16x8 v = *(const u16x8*)(prow + kk);
            const float* wbase = &sW[(q * 64 + kk) * Cv];
#pragma unroll
            for (int e = 0; e < 8; ++e) {
                const float xv = bf2f(v[e]);
                const float* wr_ = wbase + e * Cv;
#pragma unroll
                for (int c4 = 0; c4 < Cv; c4 += 4) {
                    f32x4 wv = *(const f32x4*)(wr_ + c4);
                    acc[c4 + 0] += xv * wv[0];
                    acc[c4 + 1] += xv * wv[1];
                    acc[c4 + 2] += xv * wv[2];
                    acc[c4 + 3] += xv * wv[3];
                }
            }
        }
    }

    if (q > 0) {
#pragma unroll
        for (int c4 = 0; c4 < Cv; c4 += 4)
            *(f32x4*)&sP[q - 1][r][c4] = *(f32x4*)&acc[c4];
    }
    __syncthreads();

    if (q == 0 && valid) {
#pragma unroll
        for (int p = 0; p < 7; ++p)
#pragma unroll
            for (int c4 = 0; c4 < Cv; c4 += 4) {
                f32x4 pv = *(const f32x4*)&sP[p][r][c4];
                acc[c4 + 0] += pv[0];
                acc[c4 + 1] += pv[1];
                acc[c4 + 2] += pv[2];
                acc[c4 + 3] += pv[3];
            }
        float m = -INFINITY;
#pragma unroll
        for (int c = 0; c < Cv; ++c) { acc[c] += sb[c]; m = fmaxf(m, acc[c]); }
        float s = 0.0f;
#pragma unroll
        for (int c = 0; c < Cv; ++c) s += expf(acc[c] - m);
        const float lse = m + logf(s);
        float* dst = out + (size_t)t * Cv;
#pragma unroll
        for (int c4 = 0; c4 < Cv; c4 += 4) {
            float o[4] = { acc[c4] - lse, acc[c4 + 1] - lse, acc[c4 + 2] - lse, acc[c4 + 3] - lse };
            *(float4*)(dst + c4) = *(float4*)o;
        }
    }
}

extern "C" void kernel_launch(void* const* d_in, const int* in_sizes, int n_in,
                              void* d_out, int out_size, void* d_ws, size_t ws_size,
                              hipStream_t stream)
{
    const float* x      = (const float*)d_in[0];
    const int*   ei0    = (const int*)d_in[1];
    const int*   ei1    = (const int*)d_in[2];
    const float* Wl_m0  = (const float*)d_in[3];
    const float* Wr_m0  = (const float*)d_in[4];
    const float* b_m0   = (const float*)d_in[5];
    const float* Wl_x0  = (const float*)d_in[6];
    const float* Wr_x0  = (const float*)d_in[7];
    const float* b_x0   = (const float*)d_in[8];
    const float* Wl_m1  = (const float*)d_in[9];
    const float* Wr_m1  = (const float*)d_in[10];
    const float* b_m1   = (const float*)d_in[11];
    const float* Wl_x1  = (const float*)d_in[12];
    const float* Wr_x1  = (const float*)d_in[13];
    const float* b_x1   = (const float*)d_in[14];
    const float* W_post = (const float*)d_in[15];
    const float* b_post = (const float*)d_in[16];
    float* out = (float*)d_out;

    const int* row0 = ei0;   // edge_index0[0]
    const int* row1 = ei1;   // edge_index1[0]

    // workspace layout
    char* ws = (char*)d_ws;
    const size_t XB = (size_t)N0v * Dv * 2;                        // 102.4 MB
    const size_t NB = (size_t)N1v * Dv * 2;                        // 25.6 MB
    unsigned short* xb  = (unsigned short*)(ws);                   // x bf16 (full table)
    unsigned short* am  = (unsigned short*)(ws + XB);
    unsigned short* ax  = (unsigned short*)(ws + XB + NB);
    unsigned short* hm  = (unsigned short*)(ws + XB + 2 * NB);
    unsigned short* hx  = (unsigned short*)(ws + XB + 3 * NB);
    unsigned short* a1m = (unsigned short*)(ws + XB + 4 * NB);
    unsigned short* a1x = a1m + (size_t)N2v * Dv;
    unsigned short* ocat = (unsigned short*)(ws + XB + 4 * NB + (size_t)2 * N2v * Dv * 2);
    unsigned short* WT0m = ocat + (size_t)N2v * 2 * Dv;
    unsigned short* WT0x = WT0m + (size_t)256 * 512;
    unsigned short* WT1m = WT0x + (size_t)256 * 512;
    unsigned short* WT1x = WT1m + (size_t)256 * 512;

    const dim3 blk(256);

    // 1) x -> bf16 table + weight transposes (one streaming dispatch)
    conv_prep_kernel<<<25000 + 1024, blk, 0, stream>>>(
        x, xb,
        Wl_m0, Wr_m0, Wl_x0, Wr_x0, Wl_m1, Wr_m1, Wl_x1, Wr_x1,
        WT0m, WT0x, WT1m, WT1x);

    // 2) layer-0 aggregation from L3-resident bf16 table
    agg0_kernel<<<N1v / 8, blk, 0, stream>>>(xb, row0, am, ax);

    // 3) layer 0 GEMMs (one dispatch, full-N tile); A2 = xb[:50000]
    gemm_mfma_kernel<1, 1><<<dim3((N1v + 127) / 128, 1, 2), blk, 0, stream>>>(
        am, ax, xb, WT0m, WT0x, b_m0, b_x0, hm, hx, N1v, Dv, 0);

    // 4) layer 1
    agg1_kernel<<<N2v / 8, blk, 0, stream>>>(hm, hx, row1, a1m, a1x);
    gemm_mfma_kernel<0, 1><<<dim3((N2v + 127) / 128, 1, 2), blk, 0, stream>>>(
        a1m, a1x, xb, WT1m, WT1x, b_m1, b_x1, ocat, ocat, N2v, 2 * Dv, Dv);

    // 5) post
    post_kernel<<<(N2v + 31) / 32, blk, 0, stream>>>(ocat, W_post, b_post, out, N2v);
}

// Round 10
// 215.390 us; speedup vs baseline: 1.4099x; 1.0076x over previous
//
#include <hip/hip_runtime.h>
#include <hip/hip_bf16.h>
#include <math.h>

#define N0v 200000
#define N1v 50000
#define N2v 10000
#define Dv  256
#define Cv  40
#define DEGv 10

typedef __attribute__((ext_vector_type(8))) short          s16x8;
typedef __attribute__((ext_vector_type(8))) unsigned short u16x8;
typedef __attribute__((ext_vector_type(4))) float          f32x4;

static __device__ __forceinline__ unsigned short f2bf(float f) {
    __hip_bfloat16 h = __float2bfloat16(f);
    return *reinterpret_cast<unsigned short*>(&h);
}
static __device__ __forceinline__ float bf2f(unsigned short u) {
    __hip_bfloat16 h = *reinterpret_cast<__hip_bfloat16*>(&u);
    return __bfloat162float(h);
}

// async global -> LDS, 16B/lane, wave-uniform LDS base + lane*16 dest
static __device__ __forceinline__ void gload16(const void* g, void* l) {
    __builtin_amdgcn_global_load_lds(
        (const __attribute__((address_space(1))) unsigned int*)g,
        (__attribute__((address_space(3))) unsigned int*)l, 16, 0, 0);
}

// ---- conv+prep: blocks [0,25000) convert x (200000x256 f32) -> xb bf16;
//      blocks [25000,26024) transpose 4 weight pairs -> WT[n][k] bf16.
__global__ __launch_bounds__(256) void conv_prep_kernel(
    const float* __restrict__ x, unsigned short* __restrict__ xb,
    const float* __restrict__ Wl0, const float* __restrict__ Wr0,
    const float* __restrict__ Wl1, const float* __restrict__ Wr1,
    const float* __restrict__ Wl2, const float* __restrict__ Wr2,
    const float* __restrict__ Wl3, const float* __restrict__ Wr3,
    unsigned short* __restrict__ WT0, unsigned short* __restrict__ WT1,
    unsigned short* __restrict__ WT2, unsigned short* __restrict__ WT3)
{
    const int b = blockIdx.x;
    const int tid = threadIdx.x;
    if (b < 25000) {
        const size_t i = ((size_t)b * 256 + tid) * 8;
        float4 v0 = *(const float4*)(x + i);
        float4 v1 = *(const float4*)(x + i + 4);
        unsigned short o[8] = { f2bf(v0.x), f2bf(v0.y), f2bf(v0.z), f2bf(v0.w),
                                f2bf(v1.x), f2bf(v1.y), f2bf(v1.z), f2bf(v1.w) };
        *(u16x8*)(xb + i) = *(u16x8*)o;
    } else {
        const int idx = b - 25000;
        const int p = idx >> 8;
        const int n = idx & 255;
        const float* Wl = (p == 0) ? Wl0 : (p == 1) ? Wl1 : (p == 2) ? Wl2 : Wl3;
        const float* Wr = (p == 0) ? Wr0 : (p == 1) ? Wr1 : (p == 2) ? Wr2 : Wr3;
        unsigned short* WT = (p == 0) ? WT0 : (p == 1) ? WT1 : (p == 2) ? WT2 : WT3;
        WT[(size_t)n * 512 + tid]       = f2bf(Wl[(size_t)tid * Dv + n]);
        WT[(size_t)n * 512 + 256 + tid] = f2bf(Wr[(size_t)tid * Dv + n]);
    }
}

// ---- layer-0 aggregation from bf16 table: one load feeds mean AND max.
__global__ __launch_bounds__(256) void agg0_kernel(
    const unsigned short* __restrict__ xb, const int* __restrict__ row,
    unsigned short* __restrict__ om, unsigned short* __restrict__ ox)
{
    const int t = blockIdx.x * 8 + (threadIdx.x >> 5);
    const int c = threadIdx.x & 31;
    const int eb = t * DEGv;
    float s[8] = {};
    float mx[8] = { -INFINITY, -INFINITY, -INFINITY, -INFINITY,
                    -INFINITY, -INFINITY, -INFINITY, -INFINITY };
#pragma unroll
    for (int k = 0; k < DEGv; ++k) {
        const int r = row[eb + k];
        u16x8 v = ((const u16x8*)xb)[(size_t)r * 32 + c];
#pragma unroll
        for (int j = 0; j < 8; ++j) {
            const float f = bf2f(v[j]);
            s[j] += f;
            mx[j] = fmaxf(mx[j], f);
        }
    }
    const float inv = 1.0f / DEGv;
    unsigned short osum[8], omax[8];
#pragma unroll
    for (int j = 0; j < 8; ++j) { osum[j] = f2bf(s[j] * inv); omax[j] = f2bf(mx[j]); }
    *(u16x8*)&om[(size_t)t * Dv + c * 8] = *(u16x8*)osum;
    *(u16x8*)&ox[(size_t)t * Dv + c * 8] = *(u16x8*)omax;
}

// ---- layer-1 aggregation: gather bf16 (u16x8/lane), write mean & max bf16
__global__ __launch_bounds__(256) void agg1_kernel(
    const unsigned short* __restrict__ hm, const unsigned short* __restrict__ hx,
    const int* __restrict__ row,
    unsigned short* __restrict__ om, unsigned short* __restrict__ ox)
{
    const int t = blockIdx.x * 8 + (threadIdx.x >> 5);
    const int c = threadIdx.x & 31;
    const int eb = t * DEGv;
    float s[8] = {};
    float mx[8] = { -INFINITY, -INFINITY, -INFINITY, -INFINITY,
                    -INFINITY, -INFINITY, -INFINITY, -INFINITY };
#pragma unroll
    for (int k = 0; k < DEGv; ++k) {
        const int r = row[eb + k];
        u16x8 vm = ((const u16x8*)hm)[(size_t)r * 32 + c];
        u16x8 vx = ((const u16x8*)hx)[(size_t)r * 32 + c];
#pragma unroll
        for (int j = 0; j < 8; ++j) {
            s[j]  += bf2f(vm[j]);
            mx[j]  = fmaxf(mx[j], bf2f(vx[j]));
        }
    }
    const float inv = 1.0f / DEGv;
    unsigned short osum[8], omax[8];
#pragma unroll
    for (int j = 0; j < 8; ++j) { osum[j] = f2bf(s[j] * inv); omax[j] = f2bf(mx[j]); }
    *(u16x8*)&om[(size_t)t * Dv + c * 8] = *(u16x8*)osum;
    *(u16x8*)&ox[(size_t)t * Dv + c * 8] = *(u16x8*)omax;
}

// ---- bf16 MFMA GEMM, counted-vmcnt 2-deep pipeline (T3/T4-minimal):
// out_z = [relu]( [A1_z|A2] (Mx512) @ WT_z^T + bias_z )
// BM=128, BN=256, BK=32, 512 threads = 8 waves (2M x 4N), wave-tile 64x64.
// LDS paired-line layout: line L (64 elems) = rows {2L,2L+1} x 32 k; phys
// 8-elem slot s of line L holds logical sig = s ^ (L&7), sig = (row&1)*4 + q.
// Staging: 3 x gload16/thread/stage, linear dest, pre-swizzled source.
// Schedule/iter: vmcnt(3); barrier; ds_read+16 MFMA; lgkmcnt(0); barrier;
// STAGE(t+2).  vmcnt never drains to 0 in the main loop.
template<int RELU, int OUTBF>
__global__ __launch_bounds__(512) void gemm_pipe_kernel(
    const unsigned short* __restrict__ A1a, const unsigned short* __restrict__ A1b,
    const unsigned short* __restrict__ A2,
    const unsigned short* __restrict__ WTa, const unsigned short* __restrict__ WTb,
    const float* __restrict__ biasa, const float* __restrict__ biasb,
    void* outa, void* outb, int M, int ldc, int col_step)
{
    __shared__ unsigned short Asb[2][4096];   // 2 x 8 KB  (128 rows x 32 k)
    __shared__ unsigned short Bsb[2][8192];   // 2 x 16 KB (256 rows x 32 k)

    const int z = blockIdx.z;
    const unsigned short* A1 = z ? A1b : A1a;
    const unsigned short* WT = z ? WTb : WTa;
    const float* bias = z ? biasb : biasa;
    void* outp = z ? outb : outa;
    const int col_off = z * col_step;

    const int tid  = threadIdx.x;
    const int lane = tid & 63;
    const int w    = tid >> 6;
    const int wrow = w >> 2;          // 0..1 (x64 rows)
    const int wcol = w & 3;           // 0..3 (x64 cols)
    const int m0   = blockIdx.x * 128;

    // A staging descriptor: 1 position/thread (512 x 16B = 8 KB)
    const unsigned short *pA1s, *pA2s;
    {
        const int L = tid >> 3, s = tid & 7;
        const int sig = s ^ (L & 7);
        int gm = m0 + 2 * L + (sig >> 2);
        if (gm >= M) gm = M - 1;
        pA1s = A1 + (size_t)gm * Dv + ((sig & 3) << 3);
        pA2s = A2 + (size_t)gm * Dv + ((sig & 3) << 3);
    }
    // B staging: 2 positions/thread (1024 x 16B = 16 KB)
    const unsigned short* pBs[2];
#pragma unroll
    for (int c = 0; c < 2; ++c) {
        const int p = tid + c * 512;
        const int L = p >> 3, s = p & 7;
        const int sig = s ^ (L & 7);
        pBs[c] = WT + (size_t)(2 * L + (sig >> 2)) * 512 + ((sig & 3) << 3);
    }

#define STAGE(bufv, k0v)                                                      \
    {                                                                         \
        if ((k0v) < 256) gload16(pA1s + (k0v), &Asb[bufv][tid * 8]);          \
        else             gload16(pA2s + ((k0v) - 256), &Asb[bufv][tid * 8]);  \
        gload16(pBs[0] + (k0v), &Bsb[bufv][tid * 8]);                         \
        gload16(pBs[1] + (k0v), &Bsb[bufv][(tid + 512) * 8]);                 \
    }

    // fragment read offsets (per-lane constants)
    const int q  = lane >> 4;
    const int fr = lane & 15;
    int aoff[4], boff[4];
#pragma unroll
    for (int i = 0; i < 4; ++i) {
        const int r = wrow * 64 + i * 16 + fr;
        const int L = r >> 1;
        aoff[i] = L * 64 + (((((r & 1) << 2) + q) ^ (L & 7)) << 3);
        const int n = wcol * 64 + i * 16 + fr;
        const int Lb = n >> 1;
        boff[i] = Lb * 64 + (((((n & 1) << 2) + q) ^ (Lb & 7)) << 3);
    }

    f32x4 acc[4][4] = {};

    STAGE(0, 0);
    asm volatile("" ::: "memory");    // pin vmcnt issue order between stages
    STAGE(1, 32);

#pragma unroll
    for (int t = 0; t < 16; ++t) {
        if (t < 15) asm volatile("s_waitcnt vmcnt(3)" ::: "memory");
        else        asm volatile("s_waitcnt vmcnt(0)" ::: "memory");
        __builtin_amdgcn_s_barrier();            // tile t fully in LDS

        const int cur = t & 1;
        s16x8 af[4], bfv[4];
#pragma unroll
        for (int i = 0; i < 4; ++i) {
            af[i]  = *(const s16x8*)&Asb[cur][aoff[i]];
            bfv[i] = *(const s16x8*)&Bsb[cur][boff[i]];
        }
#pragma unroll
        for (int j = 0; j < 4; ++j)
#pragma unroll
            for (int i = 0; i < 4; ++i)
                acc[i][j] = __builtin_amdgcn_mfma_f32_16x16x32_bf16(af[i], bfv[j], acc[i][j], 0, 0, 0);

        asm volatile("s_waitcnt lgkmcnt(0)" ::: "memory");  // my ds_reads landed
        __builtin_amdgcn_s_barrier();                       // all waves done with buf
        if (t < 14) STAGE(t & 1, (t + 2) * 32);             // overwrite is now safe
    }
#undef STAGE

    // epilogue: C/D map col=lane&15, row=(lane>>4)*4+reg
#pragma unroll
    for (int i = 0; i < 4; ++i) {
#pragma unroll
        for (int reg = 0; reg < 4; ++reg) {
            const int gr = m0 + wrow * 64 + i * 16 + q * 4 + reg;
            if (gr < M) {
#pragma unroll
                for (int j = 0; j < 4; ++j) {
                    const int gc = wcol * 64 + j * 16 + fr;
                    float v = acc[i][j][reg] + bias[gc];
                    if (RELU) v = fmaxf(v, 0.0f);
                    if (OUTBF)
                        ((unsigned short*)outp)[(size_t)gr * ldc + col_off + gc] = f2bf(v);
                    else
                        ((float*)outp)[(size_t)gr * ldc + col_off + gc] = v;
                }
            }
        }
    }
}

// ---- post: logits = ocat(bf16, 10000x512) @ W_post(512x40) + b_post; log_softmax.
__global__ __launch_bounds__(256) void post_kernel(
    const unsigned short* __restrict__ ocat, const float* __restrict__ Wp,
    const float* __restrict__ bp, float* __restrict__ out, int nrows)
{
    __shared__ float sW[512 * 40];        // 80 KB
    __shared__ float sP[7][32][40];       // 35 KB partials (q=1..7)
    __shared__ float sb[Cv];

    const int tid = threadIdx.x;

    for (int i = tid; i < 5120; i += 256)
        ((float4*)sW)[i] = ((const float4*)Wp)[i];
    if (tid < Cv) sb[tid] = bp[tid];
    __syncthreads();

    const int q = tid >> 5;               // k-split 0..7 (64 k each)
    const int r = tid & 31;               // local row
    const int t = blockIdx.x * 32 + r;
    const bool valid = (t < nrows);

    float acc[Cv] = {};
    if (valid) {
        const unsigned short* prow = ocat + (size_t)t * 512 + q * 64;
        for (int kk = 0; kk < 64; kk += 8) {
            u16x8 v = *(const u16x8*)(prow + kk);
            const float* wbase = &sW[(q * 64 + kk) * Cv];
#pragma unroll
            for (int e = 0; e < 8; ++e) {
                const float xv = bf2f(v[e]);
                const float* wr_ = wbase + e * Cv;
#pragma unroll
                for (int c4 = 0; c4 < Cv; c4 += 4) {
                    f32x4 wv = *(const f32x4*)(wr_ + c4);
                    acc[c4 + 0] += xv * wv[0];
                    acc[c4 + 1] += xv * wv[1];
                    acc[c4 + 2] += xv * wv[2];
                    acc[c4 + 3] += xv * wv[3];
                }
            }
        }
    }

    if (q > 0) {
#pragma unroll
        for (int c4 = 0; c4 < Cv; c4 += 4)
            *(f32x4*)&sP[q - 1][r][c4] = *(f32x4*)&acc[c4];
    }
    __syncthreads();

    if (q == 0 && valid) {
#pragma unroll
        for (int p = 0; p < 7; ++p)
#pragma unroll
            for (int c4 = 0; c4 < Cv; c4 += 4) {
                f32x4 pv = *(const f32x4*)&sP[p][r][c4];
                acc[c4 + 0] += pv[0];
                acc[c4 + 1] += pv[1];
                acc[c4 + 2] += pv[2];
                acc[c4 + 3] += pv[3];
            }
        float m = -INFINITY;
#pragma unroll
        for (int c = 0; c < Cv; ++c) { acc[c] += sb[c]; m = fmaxf(m, acc[c]); }
        float s = 0.0f;
#pragma unroll
        for (int c = 0; c < Cv; ++c) s += expf(acc[c] - m);
        const float lse = m + logf(s);
        float* dst = out + (size_t)t * Cv;
#pragma unroll
        for (int c4 = 0; c4 < Cv; c4 += 4) {
            float o[4] = { acc[c4] - lse, acc[c4 + 1] - lse, acc[c4 + 2] - lse, acc[c4 + 3] - lse };
            *(float4*)(dst + c4) = *(float4*)o;
        }
    }
}

extern "C" void kernel_launch(void* const* d_in, const int* in_sizes, int n_in,
                              void* d_out, int out_size, void* d_ws, size_t ws_size,
                              hipStream_t stream)
{
    const float* x      = (const float*)d_in[0];
    const int*   ei0    = (const int*)d_in[1];
    const int*   ei1    = (const int*)d_in[2];
    const float* Wl_m0  = (const float*)d_in[3];
    const float* Wr_m0  = (const float*)d_in[4];
    const float* b_m0   = (const float*)d_in[5];
    const float* Wl_x0  = (const float*)d_in[6];
    const float* Wr_x0  = (const float*)d_in[7];
    const float* b_x0   = (const float*)d_in[8];
    const float* Wl_m1  = (const float*)d_in[9];
    const float* Wr_m1  = (const float*)d_in[10];
    const float* b_m1   = (const float*)d_in[11];
    const float* Wl_x1  = (const float*)d_in[12];
    const float* Wr_x1  = (const float*)d_in[13];
    const float* b_x1   = (const float*)d_in[14];
    const float* W_post = (const float*)d_in[15];
    const float* b_post = (const float*)d_in[16];
    float* out = (float*)d_out;

    const int* row0 = ei0;   // edge_index0[0]
    const int* row1 = ei1;   // edge_index1[0]

    // workspace layout
    char* ws = (char*)d_ws;
    const size_t XB = (size_t)N0v * Dv * 2;                        // 102.4 MB
    const size_t NB = (size_t)N1v * Dv * 2;                        // 25.6 MB
    unsigned short* xb  = (unsigned short*)(ws);                   // x bf16 (full table)
    unsigned short* am  = (unsigned short*)(ws + XB);
    unsigned short* ax  = (unsigned short*)(ws + XB + NB);
    unsigned short* hm  = (unsigned short*)(ws + XB + 2 * NB);
    unsigned short* hx  = (unsigned short*)(ws + XB + 3 * NB);
    unsigned short* a1m = (unsigned short*)(ws + XB + 4 * NB);
    unsigned short* a1x = a1m + (size_t)N2v * Dv;
    unsigned short* ocat = (unsigned short*)(ws + XB + 4 * NB + (size_t)2 * N2v * Dv * 2);
    unsigned short* WT0m = ocat + (size_t)N2v * 2 * Dv;
    unsigned short* WT0x = WT0m + (size_t)256 * 512;
    unsigned short* WT1m = WT0x + (size_t)256 * 512;
    unsigned short* WT1x = WT1m + (size_t)256 * 512;

    const dim3 blk(256);

    // 1) x -> bf16 table + weight transposes (one streaming dispatch)
    conv_prep_kernel<<<25000 + 1024, blk, 0, stream>>>(
        x, xb,
        Wl_m0, Wr_m0, Wl_x0, Wr_x0, Wl_m1, Wr_m1, Wl_x1, Wr_x1,
        WT0m, WT0x, WT1m, WT1x);

    // 2) layer-0 aggregation from L3-resident bf16 table
    agg0_kernel<<<N1v / 8, blk, 0, stream>>>(xb, row0, am, ax);

    // 3) layer 0 GEMMs (one dispatch, pipelined); A2 = xb[:50000]
    gemm_pipe_kernel<1, 1><<<dim3((N1v + 127) / 128, 1, 2), dim3(512), 0, stream>>>(
        am, ax, xb, WT0m, WT0x, b_m0, b_x0, hm, hx, N1v, Dv, 0);

    // 4) layer 1
    agg1_kernel<<<N2v / 8, blk, 0, stream>>>(hm, hx, row1, a1m, a1x);
    gemm_pipe_kernel<0, 1><<<dim3((N2v + 127) / 128, 1, 2), dim3(512), 0, stream>>>(
        a1m, a1x, xb, WT1m, WT1x, b_m1, b_x1, ocat, ocat, N2v, 2 * Dv, Dv);

    // 5) post
    post_kernel<<<(N2v + 31) / 32, blk, 0, stream>>>(ocat, W_post, b_post, out, N2v);
}